// Round 8
// baseline (327.279 us; speedup 1.0000x reference)
//
#include <hip/hip_runtime.h>
#include <hip/hip_bf16.h>

#define E_NUM 16
#define HDIM 1024
#define IDIM 1024
#define BM 256           // one m-tile per expert (cnt<=256 typical) -> weights read once
#define BN 32
#define BK 32
#define NT 32            // IDIM/BN == HDIM/BN
#define NKT 32           // K/BK
#define MT_MAX 2         // capacity 512 rows/expert
#define SLOTS (MT_MAX * BM)
#define AKP 40           // padded LDS row stride in shorts (80 B): 16B-aligned rows, 2-way banks max

typedef short bf16x8 __attribute__((ext_vector_type(8)));
typedef float f32x4 __attribute__((ext_vector_type(4)));

__device__ __forceinline__ unsigned short f2bf(float f) {
    return __builtin_bit_cast(unsigned short, __float2bfloat16(f));
}

// ---------------- routing: bucket token ids by expert ----------------
__global__ void route_kernel(const int* __restrict__ eidx, int n_tok,
                             int* __restrict__ counts, int* __restrict__ tlist) {
    __shared__ int sc[E_NUM];
    int t = threadIdx.x;
    if (t < E_NUM) sc[t] = 0;
    __syncthreads();
    for (int n = t; n < n_tok; n += blockDim.x) {
        int e = eidx[n];
        if (e >= 0 && e < E_NUM) {
            int p = atomicAdd(&sc[e], 1);
            if (p < SLOTS) tlist[e * SLOTS + p] = n;
        }
    }
    __syncthreads();
    if (t < E_NUM) counts[t] = sc[t] > SLOTS ? SLOTS : sc[t];
}

// ---------------- gather: x_s[slot] = bf16(x[tlist[slot]]) (expert-sorted, contiguous) ----------------
__global__ __launch_bounds__(256) void gather_kernel(
    const float* __restrict__ x, const int* __restrict__ counts,
    const int* __restrict__ tlist, unsigned short* __restrict__ x_s, int n_tok)
{
    int slot = blockIdx.x;
    int e = slot >> 9;                 // / SLOTS (512)
    int p = slot & (SLOTS - 1);
    int cnt = counts[e];
    if (p >= cnt) return;
    int tk = tlist[slot];
    if (tk < 0 || tk >= n_tok) return;
    const float* src = x + (size_t)tk * HDIM;
    unsigned short* dst = x_s + (size_t)slot * HDIM;
    int t = threadIdx.x;
    float4 v = *(const float4*)(src + t * 4);
    ushort4 b;
    b.x = f2bf(v.x); b.y = f2bf(v.y); b.z = f2bf(v.z); b.w = f2bf(v.w);
    *(ushort4*)(dst + t * 4) = b;
}

// ---------------- phase 1: gate/up GEMMs + silu*mul -> inter_s (bf16, sorted) ----------------
__global__ __launch_bounds__(512) void gateup_kernel(
    const unsigned short* __restrict__ x_s, const float* __restrict__ Wg,
    const float* __restrict__ Wu, const int* __restrict__ counts,
    unsigned short* __restrict__ inter_s)
{
    int bid = blockIdx.x;
    int e = bid / (MT_MAX * NT);
    int rem = bid % (MT_MAX * NT);
    int mt = rem / NT, nt = rem % NT;
    int cnt = counts[e];
    if (cnt < 0) cnt = 0;
    if (cnt > SLOTS) cnt = SLOTS;
    int row0 = mt * BM;
    if (row0 >= cnt) return;
    int rows = cnt - row0; if (rows > BM) rows = BM;
    int n0 = nt * BN;
    int slot0 = e * SLOTS + row0;

    __shared__ __align__(16) unsigned short As[2][BM][AKP];      // 40 KB
    __shared__ __align__(16) unsigned short Bs[2][2][BN][AKP];   // 10 KB

    int t = threadIdx.x;
    int wid = t >> 6, lane = t & 63;

    // A: 2 threads/row, 16 bf16 each (2x uint4)
    int ar = t >> 1, ah = (t & 1) * 16;
    const unsigned short* ap = x_s + (size_t)(slot0 + ar) * HDIM + ah;
    // B: thread -> (mat, k-row, 4 n's); float4 read is 128B-coalesced per 16 lanes
    int bmat = t >> 8, bkk = (t >> 3) & 31, bn4 = (t & 7) * 4;
    const float* wb = (bmat ? Wu : Wg) + (size_t)e * HDIM * IDIM + n0 + bn4;

    uint4 Ar0, Ar1;
    float4 Br;

    auto loadA = [&](int kt) {
        Ar0 = *(const uint4*)(ap + kt * BK);
        Ar1 = *(const uint4*)(ap + kt * BK + 8);
    };
    auto storeA = [&](int buf) {
        *(uint4*)&As[buf][ar][ah] = Ar0;
        *(uint4*)&As[buf][ar][ah + 8] = Ar1;
    };
    auto loadB = [&](int kt) {
        Br = *(const float4*)(wb + (size_t)(kt * BK + bkk) * IDIM);
    };
    auto storeB = [&](int buf) {
        Bs[buf][bmat][bn4 + 0][bkk] = f2bf(Br.x);
        Bs[buf][bmat][bn4 + 1][bkk] = f2bf(Br.y);
        Bs[buf][bmat][bn4 + 2][bkk] = f2bf(Br.z);
        Bs[buf][bmat][bn4 + 3][bkk] = f2bf(Br.w);
    };

    int lr = lane & 15, lk = lane >> 4, lk8 = lk * 8;
    f32x4 ag[2][2] = {};
    f32x4 au[2][2] = {};

    loadA(0); loadB(0);
    storeA(0); storeB(0);
    __syncthreads();

    for (int kt = 0; kt < NKT; ++kt) {
        int cur = kt & 1, nxt = cur ^ 1;
        if (kt + 1 < NKT) { loadA(kt + 1); loadB(kt + 1); }
        bf16x8 a0 = *(const bf16x8*)&As[cur][wid * 32 + lr][lk8];
        bf16x8 a1 = *(const bf16x8*)&As[cur][wid * 32 + 16 + lr][lk8];
        bf16x8 g0 = *(const bf16x8*)&Bs[cur][0][lr][lk8];
        bf16x8 g1 = *(const bf16x8*)&Bs[cur][0][16 + lr][lk8];
        bf16x8 u0 = *(const bf16x8*)&Bs[cur][1][lr][lk8];
        bf16x8 u1 = *(const bf16x8*)&Bs[cur][1][16 + lr][lk8];
        ag[0][0] = __builtin_amdgcn_mfma_f32_16x16x32_bf16(a0, g0, ag[0][0], 0, 0, 0);
        ag[1][0] = __builtin_amdgcn_mfma_f32_16x16x32_bf16(a1, g0, ag[1][0], 0, 0, 0);
        ag[0][1] = __builtin_amdgcn_mfma_f32_16x16x32_bf16(a0, g1, ag[0][1], 0, 0, 0);
        ag[1][1] = __builtin_amdgcn_mfma_f32_16x16x32_bf16(a1, g1, ag[1][1], 0, 0, 0);
        au[0][0] = __builtin_amdgcn_mfma_f32_16x16x32_bf16(a0, u0, au[0][0], 0, 0, 0);
        au[1][0] = __builtin_amdgcn_mfma_f32_16x16x32_bf16(a1, u0, au[1][0], 0, 0, 0);
        au[0][1] = __builtin_amdgcn_mfma_f32_16x16x32_bf16(a0, u1, au[0][1], 0, 0, 0);
        au[1][1] = __builtin_amdgcn_mfma_f32_16x16x32_bf16(a1, u1, au[1][1], 0, 0, 0);
        if (kt + 1 < NKT) { storeA(nxt); storeB(nxt); }
        __syncthreads();
    }

    #pragma unroll
    for (int fm = 0; fm < 2; ++fm) {
        #pragma unroll
        for (int rr = 0; rr < 4; ++rr) {
            int row = wid * 32 + fm * 16 + lk * 4 + rr;
            if (row < rows) {
                #pragma unroll
                for (int fn = 0; fn < 2; ++fn) {
                    float g = ag[fm][fn][rr];
                    float u = au[fm][fn][rr];
                    float s = g / (1.0f + __expf(-g)) * u;
                    inter_s[(size_t)(slot0 + row) * IDIM + n0 + fn * 16 + lr] = f2bf(s);
                }
            }
        }
    }
}

// ---------------- phase 2: out[tok] = inter_s @ down^T (k contiguous in Wd) ----------------
__global__ __launch_bounds__(512) void down_kernel(
    const unsigned short* __restrict__ inter_s, const float* __restrict__ Wd,
    const int* __restrict__ counts, const int* __restrict__ tlist,
    float* __restrict__ out, int n_tok)
{
    int bid = blockIdx.x;
    int e = bid / (MT_MAX * NT);
    int rem = bid % (MT_MAX * NT);
    int mt = rem / NT, jt = rem % NT;
    int cnt = counts[e];
    if (cnt < 0) cnt = 0;
    if (cnt > SLOTS) cnt = SLOTS;
    int row0 = mt * BM;
    if (row0 >= cnt) return;
    int rows = cnt - row0; if (rows > BM) rows = BM;
    int j0 = jt * BN;
    int slot0 = e * SLOTS + row0;

    __shared__ __align__(16) unsigned short As[2][BM][AKP];   // 40 KB
    __shared__ __align__(16) unsigned short Bs[2][BN][AKP];   // 5 KB
    __shared__ int tok[BM];

    int t = threadIdx.x;
    for (int i = t; i < BM; i += 512) {
        int tk = (i < rows) ? tlist[slot0 + i] : -1;
        tok[i] = (tk >= 0 && tk < n_tok) ? tk : -1;
    }

    int wid = t >> 6, lane = t & 63;
    int ar = t >> 1, ah = (t & 1) * 16;
    const unsigned short* ap = inter_s + (size_t)(slot0 + ar) * IDIM + ah;
    // B: threads 0..255, j = t>>3, k-quad = (t&7)*4 (k contiguous in Wd)
    int bj = (t >> 3) & 31, bk4 = (t & 7) * 4;
    const float* wdp = Wd + (size_t)e * IDIM * HDIM + (size_t)(j0 + bj) * HDIM + bk4;

    uint4 Ar0, Ar1;
    float4 Br;

    auto loadA = [&](int kt) {
        Ar0 = *(const uint4*)(ap + kt * BK);
        Ar1 = *(const uint4*)(ap + kt * BK + 8);
    };
    auto storeA = [&](int buf) {
        *(uint4*)&As[buf][ar][ah] = Ar0;
        *(uint4*)&As[buf][ar][ah + 8] = Ar1;
    };
    auto loadB = [&](int kt) { if (t < 256) Br = *(const float4*)(wdp + kt * BK); };
    auto storeB = [&](int buf) {
        if (t < 256) {
            ushort4 b;
            b.x = f2bf(Br.x); b.y = f2bf(Br.y); b.z = f2bf(Br.z); b.w = f2bf(Br.w);
            *(ushort4*)&Bs[buf][bj][bk4] = b;
        }
    };

    int lr = lane & 15, lk = lane >> 4, lk8 = lk * 8;
    f32x4 acc[2][2] = {};

    loadA(0); loadB(0);
    __syncthreads();   // tok[] ready + first tile staged below
    storeA(0); storeB(0);
    __syncthreads();

    for (int kt = 0; kt < NKT; ++kt) {
        int cur = kt & 1, nxt = cur ^ 1;
        if (kt + 1 < NKT) { loadA(kt + 1); loadB(kt + 1); }
        bf16x8 a0 = *(const bf16x8*)&As[cur][wid * 32 + lr][lk8];
        bf16x8 a1 = *(const bf16x8*)&As[cur][wid * 32 + 16 + lr][lk8];
        bf16x8 b0 = *(const bf16x8*)&Bs[cur][lr][lk8];
        bf16x8 b1 = *(const bf16x8*)&Bs[cur][16 + lr][lk8];
        acc[0][0] = __builtin_amdgcn_mfma_f32_16x16x32_bf16(a0, b0, acc[0][0], 0, 0, 0);
        acc[1][0] = __builtin_amdgcn_mfma_f32_16x16x32_bf16(a1, b0, acc[1][0], 0, 0, 0);
        acc[0][1] = __builtin_amdgcn_mfma_f32_16x16x32_bf16(a0, b1, acc[0][1], 0, 0, 0);
        acc[1][1] = __builtin_amdgcn_mfma_f32_16x16x32_bf16(a1, b1, acc[1][1], 0, 0, 0);
        if (kt + 1 < NKT) { storeA(nxt); storeB(nxt); }
        __syncthreads();
    }

    #pragma unroll
    for (int fm = 0; fm < 2; ++fm) {
        #pragma unroll
        for (int rr = 0; rr < 4; ++rr) {
            int row = wid * 32 + fm * 16 + lk * 4 + rr;
            if (row < rows) {
                int tk = tok[row];
                if (tk >= 0) {
                    out[(size_t)tk * HDIM + j0 + lr] = acc[fm][0][rr];
                    out[(size_t)tk * HDIM + j0 + 16 + lr] = acc[fm][1][rr];
                }
            }
        }
    }
}

extern "C" void kernel_launch(void* const* d_in, const int* in_sizes, int n_in,
                              void* d_out, int out_size, void* d_ws, size_t ws_size,
                              hipStream_t stream) {
    const float* x  = (const float*)d_in[0];
    const int* eidx = (const int*)d_in[1];
    const float* Wg = (const float*)d_in[2];
    const float* Wu = (const float*)d_in[3];
    const float* Wd = (const float*)d_in[4];
    float* out = (float*)d_out;
    int n_tok = in_sizes[1];   // B*S = 2048

    char* ws = (char*)d_ws;
    size_t off_tlist  = 1024;                                  // E*SLOTS ints = 32 KB
    size_t off_xs     = (size_t)1 << 16;                       // 64 KB
    size_t sz_sorted  = (size_t)E_NUM * SLOTS * HDIM * 2;      // 16 MB
    size_t off_inter  = off_xs + sz_sorted;

    int* counts            = (int*)ws;
    int* tlist             = (int*)(ws + off_tlist);
    unsigned short* x_s    = (unsigned short*)(ws + off_xs);
    unsigned short* inter_s = (unsigned short*)(ws + off_inter);

    route_kernel<<<1, 256, 0, stream>>>(eidx, n_tok, counts, tlist);
    gather_kernel<<<E_NUM * SLOTS, 256, 0, stream>>>(x, counts, tlist, x_s, n_tok);

    int grid = E_NUM * MT_MAX * NT;   // 1024
    gateup_kernel<<<grid, 512, 0, stream>>>(x_s, Wg, Wu, counts, inter_s);
    down_kernel<<<grid, 512, 0, stream>>>(inter_s, Wd, counts, tlist, out, n_tok);
}